// Round 1
// baseline (426.788 us; speedup 1.0000x reference)
//
#include <hip/hip_runtime.h>
#include <hip/hip_bf16.h>
#include <stdint.h>

typedef __attribute__((ext_vector_type(8))) __bf16 bf16x8;
typedef __attribute__((ext_vector_type(4))) float f32x4;

#define BM 128
#define BN 128
#define BK 32

// ---------------- NVFP4 quantize-dequantize (factored: no global scale) ----------------

__device__ __forceinline__ float fp8_e4m3_rne(float x) {
  // x in [0, 448] by construction (bs = amax/(6*gs) <= 448 up to 1 ulp).
  if (x < 0.015625f) {                       // below min normal 2^-6: subnormal grid 2^-9
    return rintf(x * 512.0f) * 0.001953125f; // rintf == v_rndne (RNE)
  }
  uint32_t u = __float_as_uint(x);
  uint32_t keep = u & 0xFFF00000u;           // keep 3 mantissa bits
  uint32_t rem  = u & 0x000FFFFFu;
  uint32_t lsb  = (u >> 20) & 1u;
  if (rem > 0x80000u || (rem == 0x80000u && lsb)) keep += 0x100000u; // RNE (carry ok)
  return __uint_as_float(keep);
}

__device__ __forceinline__ float snap_lvl(float a) {
  // idx = sum(a > mids), strict >, mids = {0.25,0.75,1.25,1.75,2.5,3.5,5.0}
  if (a > 5.0f)  return 6.0f;
  if (a > 3.5f)  return 4.0f;
  if (a > 2.5f)  return 3.0f;
  if (a > 1.75f) return 2.0f;
  if (a > 1.25f) return 1.5f;
  if (a > 0.75f) return 1.0f;
  if (a > 0.25f) return 0.5f;
  return 0.0f;
}

// One thread per 16-element block: out[i] = bf16( sign * level * bs8 )  (exact in bf16)
__global__ __launch_bounds__(256) void quant_nvfp4(
    const float* __restrict__ in, unsigned short* __restrict__ out,
    const float* __restrict__ gsp, int nblk) {
  int b = blockIdx.x * 256 + threadIdx.x;
  if (b >= nblk) return;
  float gs = gsp[0];
  const float4* p = reinterpret_cast<const float4*>(in) + (size_t)b * 4;
  float v[16];
#pragma unroll
  for (int i = 0; i < 4; ++i) {
    float4 t4 = p[i];
    v[i * 4 + 0] = t4.x; v[i * 4 + 1] = t4.y;
    v[i * 4 + 2] = t4.z; v[i * 4 + 3] = t4.w;
  }
  float amax = 0.0f;
#pragma unroll
  for (int i = 0; i < 16; ++i) amax = fmaxf(amax, fabsf(v[i]));
  float bs8 = fp8_e4m3_rne(amax / (6.0f * gs));
  float scale = fmaxf(bs8 * gs, 1e-12f);
  unsigned short o[16];
#pragma unroll
  for (int i = 0; i < 16; ++i) {
    float q = v[i] / scale;                  // IEEE div, matches reference elementwise
    float a = fminf(fabsf(q), 6.0f);         // clip(|v|, 0, 6)
    float val = copysignf(snap_lvl(a) * bs8, q);
    o[i] = (unsigned short)(__float_as_uint(val) >> 16);  // exact, truncation lossless
  }
  uint4 w0 = make_uint4((uint32_t)o[0] | ((uint32_t)o[1] << 16),
                        (uint32_t)o[2] | ((uint32_t)o[3] << 16),
                        (uint32_t)o[4] | ((uint32_t)o[5] << 16),
                        (uint32_t)o[6] | ((uint32_t)o[7] << 16));
  uint4 w1 = make_uint4((uint32_t)o[8]  | ((uint32_t)o[9]  << 16),
                        (uint32_t)o[10] | ((uint32_t)o[11] << 16),
                        (uint32_t)o[12] | ((uint32_t)o[13] << 16),
                        (uint32_t)o[14] | ((uint32_t)o[15] << 16));
  uint4* op = reinterpret_cast<uint4*>(out + (size_t)b * 16);
  op[0] = w0;
  op[1] = w1;
}

// ---------------- bf16 GEMM, C = A * B^T (A: MxK, B: NxK row-major) ----------------

__device__ __forceinline__ void async_lds16(const void* g, void* l) {
  __builtin_amdgcn_global_load_lds((__attribute__((address_space(1))) void*)(g),
                                   (__attribute__((address_space(3))) void*)(l),
                                   16, 0, 0);
}

__global__ __launch_bounds__(256) void gemm_bt_bf16(
    const unsigned short* __restrict__ A, const unsigned short* __restrict__ B,
    const float* __restrict__ bias, const float* __restrict__ gsx,
    const float* __restrict__ gsw, float* __restrict__ C,
    int M, int N, int K) {
  __shared__ __align__(16) unsigned short As[BM * BK];
  __shared__ __align__(16) unsigned short Bs[BN * BK];

  const int t = threadIdx.x;
  const int w = t >> 6, l = t & 63;
  const int wm = w >> 1, wn = w & 1;           // 2x2 waves, each owns 64x64
  const int lr = l & 15, lk = (l >> 4) * 8;    // fragment row / k-offset

  // Bijective XCD swizzle (nwg = 2048, divisible by 8)
  const int nbn = N / BN;
  const int nwg = (M / BM) * nbn;
  const int cpx = nwg >> 3;
  int bid = blockIdx.x;
  int logical = (bid & 7) * cpx + (bid >> 3);
  const int bm = logical / nbn, bn = logical % nbn;
  const int brow = bm * BM, bcol = bn * BN;

  f32x4 acc[4][4] = {};

  float bias_r[4];
#pragma unroll
  for (int ni = 0; ni < 4; ++ni)
    bias_r[ni] = bias[bcol + wn * 64 + ni * 16 + lr];

  for (int k0 = 0; k0 < K; k0 += BK) {
#pragma unroll
    for (int it = 0; it < 2; ++it) {
      int c = t + it * 256;                    // chunk id, 512 x 16B per tile
      int row = c >> 2, kc = c & 3;
      const unsigned short* ga = A + (size_t)(brow + row) * K + (k0 + kc * 8);
      async_lds16((const void*)ga, (void*)(As + c * 8));
      const unsigned short* gb = B + (size_t)(bcol + row) * K + (k0 + kc * 8);
      async_lds16((const void*)gb, (void*)(Bs + c * 8));
    }
    __syncthreads();                            // drains vmcnt before barrier

    bf16x8 af[4], bf[4];
#pragma unroll
    for (int mi = 0; mi < 4; ++mi)
      af[mi] = *reinterpret_cast<const bf16x8*>(&As[(wm * 64 + mi * 16 + lr) * BK + lk]);
#pragma unroll
    for (int ni = 0; ni < 4; ++ni)
      bf[ni] = *reinterpret_cast<const bf16x8*>(&Bs[(wn * 64 + ni * 16 + lr) * BK + lk]);
#pragma unroll
    for (int mi = 0; mi < 4; ++mi)
#pragma unroll
      for (int ni = 0; ni < 4; ++ni)
        acc[mi][ni] = __builtin_amdgcn_mfma_f32_16x16x32_bf16(af[mi], bf[ni], acc[mi][ni], 0, 0, 0);
    __syncthreads();
  }

  const float gscale = gsx[0] * gsw[0];
#pragma unroll
  for (int mi = 0; mi < 4; ++mi) {
#pragma unroll
    for (int ni = 0; ni < 4; ++ni) {
#pragma unroll
      for (int r = 0; r < 4; ++r) {
        int row = brow + wm * 64 + mi * 16 + (l >> 4) * 4 + r;  // C/D: row=(lane>>4)*4+reg
        int col = bcol + wn * 64 + ni * 16 + lr;                // col=lane&15
        C[(size_t)row * N + col] = acc[mi][ni][r] * gscale + bias_r[ni];
      }
    }
  }
}

// ---------------- launch ----------------

extern "C" void kernel_launch(void* const* d_in, const int* in_sizes, int n_in,
                              void* d_out, int out_size, void* d_ws, size_t ws_size,
                              hipStream_t stream) {
  const float* x    = (const float*)d_in[0];
  const float* wgt  = (const float*)d_in[1];
  const float* bias = (const float*)d_in[2];
  const float* isc  = (const float*)d_in[3];
  const float* wsc  = (const float*)d_in[4];
  float* out = (float*)d_out;

  const int N = in_sizes[2];            // 4096
  const int K = in_sizes[1] / N;        // 4096
  const int M = in_sizes[0] / K;        // 8192

  unsigned short* Aq = (unsigned short*)d_ws;
  unsigned short* Bq = Aq + (size_t)M * K;

  int nblkA = M * K / 16;
  quant_nvfp4<<<(nblkA + 255) / 256, 256, 0, stream>>>(x, Aq, isc, nblkA);
  int nblkB = N * K / 16;
  quant_nvfp4<<<(nblkB + 255) / 256, 256, 0, stream>>>(wgt, Bq, wsc, nblkB);

  dim3 grid((M / BM) * (N / BN));
  gemm_bt_bf16<<<grid, 256, 0, stream>>>(Aq, Bq, bias, isc, wsc, out, M, N, K);
}

// Round 2
// 361.358 us; speedup vs baseline: 1.1811x; 1.1811x over previous
//
#include <hip/hip_runtime.h>
#include <hip/hip_bf16.h>
#include <stdint.h>

typedef __attribute__((ext_vector_type(8))) __bf16 bf16x8;
typedef __attribute__((ext_vector_type(4))) float f32x4;

#define BM 256
#define BN 256
#define BKS 32            // K-depth per subtile/phase (= one MFMA K)
#define RING 4            // LDS ring slots (prefetch depth 3)

// ---------------- NVFP4 quantize-dequantize (factored: no global scale) ----------------

__device__ __forceinline__ float fp8_e4m3_rne(float x) {
  if (x < 0.015625f) {                       // below min normal 2^-6: subnormal grid 2^-9
    return rintf(x * 512.0f) * 0.001953125f;
  }
  uint32_t u = __float_as_uint(x);
  uint32_t keep = u & 0xFFF00000u;
  uint32_t rem  = u & 0x000FFFFFu;
  uint32_t lsb  = (u >> 20) & 1u;
  if (rem > 0x80000u || (rem == 0x80000u && lsb)) keep += 0x100000u;
  return __uint_as_float(keep);
}

__device__ __forceinline__ float snap_lvl(float a) {
  if (a > 5.0f)  return 6.0f;
  if (a > 3.5f)  return 4.0f;
  if (a > 2.5f)  return 3.0f;
  if (a > 1.75f) return 2.0f;
  if (a > 1.25f) return 1.5f;
  if (a > 0.75f) return 1.0f;
  if (a > 0.25f) return 0.5f;
  return 0.0f;
}

__global__ __launch_bounds__(256) void quant_nvfp4(
    const float* __restrict__ in, unsigned short* __restrict__ out,
    const float* __restrict__ gsp, int nblk) {
  int b = blockIdx.x * 256 + threadIdx.x;
  if (b >= nblk) return;
  float gs = gsp[0];
  const float4* p = reinterpret_cast<const float4*>(in) + (size_t)b * 4;
  float v[16];
#pragma unroll
  for (int i = 0; i < 4; ++i) {
    float4 t4 = p[i];
    v[i * 4 + 0] = t4.x; v[i * 4 + 1] = t4.y;
    v[i * 4 + 2] = t4.z; v[i * 4 + 3] = t4.w;
  }
  float amax = 0.0f;
#pragma unroll
  for (int i = 0; i < 16; ++i) amax = fmaxf(amax, fabsf(v[i]));
  float bs8 = fp8_e4m3_rne(amax / (6.0f * gs));
  float scale = fmaxf(bs8 * gs, 1e-12f);
  unsigned short o[16];
#pragma unroll
  for (int i = 0; i < 16; ++i) {
    float q = v[i] / scale;
    float a = fminf(fabsf(q), 6.0f);
    float val = copysignf(snap_lvl(a) * bs8, q);
    o[i] = (unsigned short)(__float_as_uint(val) >> 16);
  }
  uint4 w0 = make_uint4((uint32_t)o[0] | ((uint32_t)o[1] << 16),
                        (uint32_t)o[2] | ((uint32_t)o[3] << 16),
                        (uint32_t)o[4] | ((uint32_t)o[5] << 16),
                        (uint32_t)o[6] | ((uint32_t)o[7] << 16));
  uint4 w1 = make_uint4((uint32_t)o[8]  | ((uint32_t)o[9]  << 16),
                        (uint32_t)o[10] | ((uint32_t)o[11] << 16),
                        (uint32_t)o[12] | ((uint32_t)o[13] << 16),
                        (uint32_t)o[14] | ((uint32_t)o[15] << 16));
  uint4* op = reinterpret_cast<uint4*>(out + (size_t)b * 16);
  op[0] = w0;
  op[1] = w1;
}

// ---------------- bf16 GEMM, C = A * B^T ; 256x256 tile, 4-slot BK=32 ring ----------------

__device__ __forceinline__ void async_lds16(const void* g, void* l) {
  __builtin_amdgcn_global_load_lds((__attribute__((address_space(1))) void*)(g),
                                   (__attribute__((address_space(3))) void*)(l),
                                   16, 0, 0);
}

// stage subtile s of A and B into ring slot s&3 (4 x 16B per thread)
#define STAGE(s) do {                                                        \
    int _slot = (s) & (RING - 1);                                            \
    char* _la = (char*)As + _slot * 16384;                                   \
    char* _lb = (char*)Bs + _slot * 16384;                                   \
    async_lds16((const void*)(pA0 + (size_t)(s) * BKS), (void*)(_la + lo0)); \
    async_lds16((const void*)(pB0 + (size_t)(s) * BKS), (void*)(_lb + lo0)); \
    async_lds16((const void*)(pA1 + (size_t)(s) * BKS), (void*)(_la + lo1)); \
    async_lds16((const void*)(pB1 + (size_t)(s) * BKS), (void*)(_lb + lo1)); \
  } while (0)

// one pipeline phase: wait (counted) -> barrier -> prefetch s+3 -> ds_read -> 32 MFMA
#define PHASE(VMSTR, s, do_stage) do {                                       \
    asm volatile("s_waitcnt vmcnt(" VMSTR ")" ::: "memory");                 \
    __builtin_amdgcn_s_barrier();                                            \
    asm volatile("" ::: "memory");                                           \
    if (do_stage) STAGE((s) + 3);                                            \
    int _sl = (s) & (RING - 1);                                              \
    const char* _ab = (const char*)As + _sl * 16384;                         \
    const char* _bb = (const char*)Bs + _sl * 16384;                         \
    bf16x8 af[8], bfr[4];                                                    \
    _Pragma("unroll") for (int mi = 0; mi < 8; ++mi)                         \
      af[mi] = *(const bf16x8*)(_ab + offA[mi]);                             \
    _Pragma("unroll") for (int ni = 0; ni < 4; ++ni)                         \
      bfr[ni] = *(const bf16x8*)(_bb + offB[ni]);                            \
    __builtin_amdgcn_s_setprio(1);                                           \
    _Pragma("unroll") for (int mi = 0; mi < 8; ++mi)                         \
      _Pragma("unroll") for (int ni = 0; ni < 4; ++ni)                       \
        acc[mi][ni] = __builtin_amdgcn_mfma_f32_16x16x32_bf16(               \
            af[mi], bfr[ni], acc[mi][ni], 0, 0, 0);                          \
    __builtin_amdgcn_s_setprio(0);                                           \
  } while (0)

__global__ __launch_bounds__(512, 2) void gemm_bt_bf16(
    const unsigned short* __restrict__ A, const unsigned short* __restrict__ B,
    const float* __restrict__ bias, const float* __restrict__ gsx,
    const float* __restrict__ gsw, float* __restrict__ C,
    int M, int N, int K) {
  // ring: per slot A 256x32 bf16 (16 KB) + B 256x32 (16 KB); total 128 KiB
  __shared__ __align__(16) unsigned short As[RING * 8192];
  __shared__ __align__(16) unsigned short Bs[RING * 8192];

  const int t = threadIdx.x;
  const int l = t & 63;
  const int w = t >> 6;
  const int wm = w >> 2, wn = w & 3;     // 2x4 waves; wave tile = 128(M) x 64(N)

  // bijective XCD swizzle (nwg = 512, divisible by 8)
  const int nbn = N / BN;
  const int nwg = (M / BM) * nbn;
  const int cpx = nwg >> 3;
  int bid = blockIdx.x;
  int logical = (bid & 7) * cpx + (bid >> 3);
  const int bm = logical / nbn, bn = logical % nbn;
  const int brow = bm * BM, bcol = bn * BN;

  // ---- staging descriptors: LDS linear dest, inverse-swizzled global source ----
  // subtile layout [256 rows][32 k] bf16; swizzle involution: byte ^= ((byte>>7)&3)<<4
  unsigned int b0 = (unsigned int)t * 16u;
  unsigned int b1 = b0 + 8192u;
  unsigned int bp0 = b0 ^ (((b0 >> 7) & 3u) << 4);
  unsigned int bp1 = b1 ^ (((b1 >> 7) & 3u) << 4);
  const unsigned int lo0 = b0, lo1 = b1;
  const unsigned short* pA0 = A + (size_t)(brow + (bp0 >> 6)) * K + ((bp0 & 63u) >> 1);
  const unsigned short* pA1 = A + (size_t)(brow + (bp1 >> 6)) * K + ((bp1 & 63u) >> 1);
  const unsigned short* pB0 = B + (size_t)(bcol + (bp0 >> 6)) * K + ((bp0 & 63u) >> 1);
  const unsigned short* pB1 = B + (size_t)(bcol + (bp1 >> 6)) * K + ((bp1 & 63u) >> 1);

  // ---- swizzled fragment read offsets (bytes within a slot) ----
  unsigned int offA[8], offB[4];
#pragma unroll
  for (int mi = 0; mi < 8; ++mi) {
    unsigned int r = wm * 128 + mi * 16 + (l & 15);
    unsigned int q = r * 64 + ((l >> 4) << 4);
    offA[mi] = q ^ (((q >> 7) & 3u) << 4);
  }
#pragma unroll
  for (int ni = 0; ni < 4; ++ni) {
    unsigned int r = wn * 64 + ni * 16 + (l & 15);
    unsigned int q = r * 64 + ((l >> 4) << 4);
    offB[ni] = q ^ (((q >> 7) & 3u) << 4);
  }

  f32x4 acc[8][4] = {};

  float bias_r[4];
#pragma unroll
  for (int ni = 0; ni < 4; ++ni)
    bias_r[ni] = bias[bcol + wn * 64 + ni * 16 + (l & 15)];

  const int nsub = K / BKS;   // 128

  // prologue: prefetch subtiles 0..2
  STAGE(0);
  STAGE(1);
  STAGE(2);

  // steady state: vmcnt(8) leaves the 2 newest stages (8 loads) in flight
  for (int s = 0; s < nsub - 2; ++s) {
    PHASE("8", s, s + 3 < nsub);
  }
  PHASE("4", nsub - 2, false);
  PHASE("0", nsub - 1, false);

  // ---- epilogue ----
  const float gscale = gsx[0] * gsw[0];
#pragma unroll
  for (int mi = 0; mi < 8; ++mi) {
#pragma unroll
    for (int ni = 0; ni < 4; ++ni) {
#pragma unroll
      for (int r = 0; r < 4; ++r) {
        int row = brow + wm * 128 + mi * 16 + (l >> 4) * 4 + r;
        int col = bcol + wn * 64 + ni * 16 + (l & 15);
        C[(size_t)row * N + col] = acc[mi][ni][r] * gscale + bias_r[ni];
      }
    }
  }
}

// ---------------- launch ----------------

extern "C" void kernel_launch(void* const* d_in, const int* in_sizes, int n_in,
                              void* d_out, int out_size, void* d_ws, size_t ws_size,
                              hipStream_t stream) {
  const float* x    = (const float*)d_in[0];
  const float* wgt  = (const float*)d_in[1];
  const float* bias = (const float*)d_in[2];
  const float* isc  = (const float*)d_in[3];
  const float* wsc  = (const float*)d_in[4];
  float* out = (float*)d_out;

  const int N = in_sizes[2];            // 4096
  const int K = in_sizes[1] / N;        // 4096
  const int M = in_sizes[0] / K;        // 8192

  unsigned short* Aq = (unsigned short*)d_ws;
  unsigned short* Bq = Aq + (size_t)M * K;

  int nblkA = M * K / 16;
  quant_nvfp4<<<(nblkA + 255) / 256, 256, 0, stream>>>(x, Aq, isc, nblkA);
  int nblkB = N * K / 16;
  quant_nvfp4<<<(nblkB + 255) / 256, 256, 0, stream>>>(wgt, Bq, wsc, nblkB);

  dim3 grid((M / BM) * (N / BN));
  gemm_bt_bf16<<<grid, 512, 0, stream>>>(Aq, Bq, bias, isc, wsc, out, M, N, K);
}

// Round 3
// 305.889 us; speedup vs baseline: 1.3952x; 1.1813x over previous
//
#include <hip/hip_runtime.h>
#include <hip/hip_bf16.h>
#include <stdint.h>

typedef __attribute__((ext_vector_type(8))) __bf16 bf16x8;
typedef __attribute__((ext_vector_type(4))) float f32x4;

#define BM 256
#define BN 256
#define BKT 32            // K per ring slot (= one MFMA K-step)
#define RING 4            // prefetch depth 3
#define SLOT_BYTES 16384  // 256 rows x 32 cols x 2B

// ---------------- NVFP4 quantize-dequantize (factored: no global scale) ----------------

__device__ __forceinline__ float fp8_e4m3_rne(float x) {
  if (x < 0.015625f) {                       // below min normal 2^-6: subnormal grid 2^-9
    return rintf(x * 512.0f) * 0.001953125f;
  }
  uint32_t u = __float_as_uint(x);
  uint32_t keep = u & 0xFFF00000u;
  uint32_t rem  = u & 0x000FFFFFu;
  uint32_t lsb  = (u >> 20) & 1u;
  if (rem > 0x80000u || (rem == 0x80000u && lsb)) keep += 0x100000u;
  return __uint_as_float(keep);
}

__device__ __forceinline__ float snap_lvl(float a) {
  if (a > 5.0f)  return 6.0f;
  if (a > 3.5f)  return 4.0f;
  if (a > 2.5f)  return 3.0f;
  if (a > 1.75f) return 2.0f;
  if (a > 1.25f) return 1.5f;
  if (a > 0.75f) return 1.0f;
  if (a > 0.25f) return 0.5f;
  return 0.0f;
}

__global__ __launch_bounds__(256) void quant_nvfp4(
    const float* __restrict__ in, unsigned short* __restrict__ out,
    const float* __restrict__ gsp, int nblk) {
  int b = blockIdx.x * 256 + threadIdx.x;
  if (b >= nblk) return;
  float gs = gsp[0];
  const float4* p = reinterpret_cast<const float4*>(in) + (size_t)b * 4;
  float v[16];
#pragma unroll
  for (int i = 0; i < 4; ++i) {
    float4 t4 = p[i];
    v[i * 4 + 0] = t4.x; v[i * 4 + 1] = t4.y;
    v[i * 4 + 2] = t4.z; v[i * 4 + 3] = t4.w;
  }
  float amax = 0.0f;
#pragma unroll
  for (int i = 0; i < 16; ++i) amax = fmaxf(amax, fabsf(v[i]));
  float bs8 = fp8_e4m3_rne(amax / (6.0f * gs));
  float scale = fmaxf(bs8 * gs, 1e-12f);
  unsigned short o[16];
#pragma unroll
  for (int i = 0; i < 16; ++i) {
    float q = v[i] / scale;
    float a = fminf(fabsf(q), 6.0f);
    float val = copysignf(snap_lvl(a) * bs8, q);
    o[i] = (unsigned short)(__float_as_uint(val) >> 16);
  }
  uint4 w0 = make_uint4((uint32_t)o[0] | ((uint32_t)o[1] << 16),
                        (uint32_t)o[2] | ((uint32_t)o[3] << 16),
                        (uint32_t)o[4] | ((uint32_t)o[5] << 16),
                        (uint32_t)o[6] | ((uint32_t)o[7] << 16));
  uint4 w1 = make_uint4((uint32_t)o[8]  | ((uint32_t)o[9]  << 16),
                        (uint32_t)o[10] | ((uint32_t)o[11] << 16),
                        (uint32_t)o[12] | ((uint32_t)o[13] << 16),
                        (uint32_t)o[14] | ((uint32_t)o[15] << 16));
  uint4* op = reinterpret_cast<uint4*>(out + (size_t)b * 16);
  op[0] = w0;
  op[1] = w1;
}

// ---------------- bf16 GEMM, C = A * B^T ; 256x256 tile, ring-4 BK=32, 2-phase/tile ----------------

__device__ __forceinline__ void async_lds16(const void* g, void* l) {
  __builtin_amdgcn_global_load_lds((__attribute__((address_space(1))) void*)(g),
                                   (__attribute__((address_space(3))) void*)(l),
                                   16, 0, 0);
}

// PH0: read af[0..3]+bf[0..3] of slot T, stage lo-half of T+3, barrier, 16 MFMA (mi 0..3)
#define PHASE0(T, DO_STAGE) {                                                  \
    const char* _ab = (const char*)As + ((T) & 3) * SLOT_BYTES;                \
    const char* _bb = (const char*)Bs + ((T) & 3) * SLOT_BYTES;                \
    _Pragma("unroll") for (int mi = 0; mi < 4; ++mi)                           \
      af[mi] = *(const bf16x8*)(_ab + offA[mi]);                               \
    _Pragma("unroll") for (int ni = 0; ni < 4; ++ni)                           \
      bfr[ni] = *(const bf16x8*)(_bb + offB[ni]);                              \
    if (DO_STAGE) {                                                            \
      char* _la = (char*)As + (((T) + 3) & 3) * SLOT_BYTES;                    \
      char* _lb = (char*)Bs + (((T) + 3) & 3) * SLOT_BYTES;                    \
      async_lds16(pA0 + (size_t)((T) + 3) * BKT, _la + lo0);                   \
      async_lds16(pB0 + (size_t)((T) + 3) * BKT, _lb + lo0);                   \
    }                                                                          \
    __builtin_amdgcn_s_barrier();                                              \
    asm volatile("s_waitcnt lgkmcnt(0)" ::: "memory");                         \
    __builtin_amdgcn_sched_barrier(0);                                         \
    __builtin_amdgcn_s_setprio(1);                                             \
    _Pragma("unroll") for (int mi = 0; mi < 4; ++mi)                           \
      _Pragma("unroll") for (int ni = 0; ni < 4; ++ni)                         \
        acc[mi][ni] = __builtin_amdgcn_mfma_f32_16x16x32_bf16(                 \
            af[mi], bfr[ni], acc[mi][ni], 0, 0, 0);                            \
    __builtin_amdgcn_s_setprio(0);                                             \
    __builtin_amdgcn_sched_barrier(0);                                         \
    __builtin_amdgcn_s_barrier();                                              \
  }

// PH1: read af[4..7] (bf reused), stage hi-half of T+3, counted vmcnt, 16 MFMA (mi 4..7)
#define PHASE1(T, DO_STAGE, VMASM) {                                           \
    const char* _ab = (const char*)As + ((T) & 3) * SLOT_BYTES;                \
    _Pragma("unroll") for (int mi = 0; mi < 4; ++mi)                           \
      af[mi] = *(const bf16x8*)(_ab + offA[4 + mi]);                           \
    if (DO_STAGE) {                                                            \
      char* _la = (char*)As + (((T) + 3) & 3) * SLOT_BYTES;                    \
      char* _lb = (char*)Bs + (((T) + 3) & 3) * SLOT_BYTES;                    \
      async_lds16(pA1 + (size_t)((T) + 3) * BKT, _la + lo1);                   \
      async_lds16(pB1 + (size_t)((T) + 3) * BKT, _lb + lo1);                   \
    }                                                                          \
    VMASM;                                                                     \
    __builtin_amdgcn_s_barrier();                                              \
    asm volatile("s_waitcnt lgkmcnt(0)" ::: "memory");                         \
    __builtin_amdgcn_sched_barrier(0);                                         \
    __builtin_amdgcn_s_setprio(1);                                             \
    _Pragma("unroll") for (int mi = 0; mi < 4; ++mi)                           \
      _Pragma("unroll") for (int ni = 0; ni < 4; ++ni)                         \
        acc[4 + mi][ni] = __builtin_amdgcn_mfma_f32_16x16x32_bf16(             \
            af[mi], bfr[ni], acc[4 + mi][ni], 0, 0, 0);                        \
    __builtin_amdgcn_s_setprio(0);                                             \
    __builtin_amdgcn_sched_barrier(0);                                         \
    __builtin_amdgcn_s_barrier();                                              \
  }

#define STAGE_TILE(s) {                                                        \
    char* _la = (char*)As + ((s) & 3) * SLOT_BYTES;                            \
    char* _lb = (char*)Bs + ((s) & 3) * SLOT_BYTES;                            \
    async_lds16(pA0 + (size_t)(s) * BKT, _la + lo0);                           \
    async_lds16(pB0 + (size_t)(s) * BKT, _lb + lo0);                           \
    async_lds16(pA1 + (size_t)(s) * BKT, _la + lo1);                           \
    async_lds16(pB1 + (size_t)(s) * BKT, _lb + lo1);                           \
  }

__global__ __launch_bounds__(512, 2) void gemm_bt_bf16(
    const unsigned short* __restrict__ A, const unsigned short* __restrict__ B,
    const float* __restrict__ bias, const float* __restrict__ gsx,
    const float* __restrict__ gsw, float* __restrict__ C,
    int M, int N, int K) {
  __shared__ __align__(16) unsigned short As[RING * 8192];
  __shared__ __align__(16) unsigned short Bs[RING * 8192];

  const int t = threadIdx.x;
  const int l = t & 63;
  const int w = t >> 6;
  const int wm = w >> 2, wn = w & 3;     // 2x4 waves; wave tile = 128(M) x 64(N)

  // bijective XCD swizzle (nwg = 512, divisible by 8)
  const int nbn = N / BN;
  const int nwg = (M / BM) * nbn;
  const int cpx = nwg >> 3;
  int bid = blockIdx.x;
  int logical = (bid & 7) * cpx + (bid >> 3);
  const int bm = logical / nbn, bn = logical % nbn;
  const int brow = bm * BM, bcol = bn * BN;

  // staging: linear LDS dest, inverse-swizzled global source (involution q^(((q>>7)&3)<<4))
  unsigned int b0 = (unsigned int)t * 16u;
  unsigned int b1 = b0 + 8192u;
  unsigned int bp0 = b0 ^ (((b0 >> 7) & 3u) << 4);
  unsigned int bp1 = b1 ^ (((b1 >> 7) & 3u) << 4);
  const unsigned int lo0 = b0, lo1 = b1;
  const unsigned short* pA0 = A + (size_t)(brow + (bp0 >> 6)) * K + ((bp0 & 63u) >> 1);
  const unsigned short* pA1 = A + (size_t)(brow + (bp1 >> 6)) * K + ((bp1 & 63u) >> 1);
  const unsigned short* pB0 = B + (size_t)(bcol + (bp0 >> 6)) * K + ((bp0 & 63u) >> 1);
  const unsigned short* pB1 = B + (size_t)(bcol + (bp1 >> 6)) * K + ((bp1 & 63u) >> 1);

  // swizzled fragment read offsets (bytes within a slot)
  unsigned int offA[8], offB[4];
#pragma unroll
  for (int mi = 0; mi < 8; ++mi) {
    unsigned int r = wm * 128 + mi * 16 + (l & 15);
    unsigned int q = r * 64 + ((l >> 4) << 4);
    offA[mi] = q ^ (((q >> 7) & 3u) << 4);
  }
#pragma unroll
  for (int ni = 0; ni < 4; ++ni) {
    unsigned int r = wn * 64 + ni * 16 + (l & 15);
    unsigned int q = r * 64 + ((l >> 4) << 4);
    offB[ni] = q ^ (((q >> 7) & 3u) << 4);
  }

  f32x4 acc[8][4] = {};
  bf16x8 af[4], bfr[4];

  const int nsub = K / BKT;   // 128

  // prologue: stage tiles 0..2, confirm tile 0 (leave tiles 1,2 = 8 loads in flight)
  STAGE_TILE(0);
  STAGE_TILE(1);
  STAGE_TILE(2);
  asm volatile("s_waitcnt vmcnt(8)" ::: "memory");
  __builtin_amdgcn_s_barrier();

#pragma unroll 1
  for (int T = 0; T < nsub - 3; ++T) {
    PHASE0(T, 1);
    PHASE1(T, 1, asm volatile("s_waitcnt vmcnt(8)" ::: "memory"));
  }
  PHASE0(nsub - 3, 0);
  PHASE1(nsub - 3, 0, asm volatile("s_waitcnt vmcnt(4)" ::: "memory"));
  PHASE0(nsub - 2, 0);
  PHASE1(nsub - 2, 0, asm volatile("s_waitcnt vmcnt(0)" ::: "memory"));
  PHASE0(nsub - 1, 0);
  PHASE1(nsub - 1, 0, (void)0);

  // ---- epilogue (scale/bias loaded here so they never enter the loop's vmcnt window) ----
  const float gscale = gsx[0] * gsw[0];
  float bias_r[4];
#pragma unroll
  for (int ni = 0; ni < 4; ++ni)
    bias_r[ni] = bias[bcol + wn * 64 + ni * 16 + (l & 15)];
#pragma unroll
  for (int mi = 0; mi < 8; ++mi) {
#pragma unroll
    for (int ni = 0; ni < 4; ++ni) {
#pragma unroll
      for (int r = 0; r < 4; ++r) {
        int row = brow + wm * 128 + mi * 16 + (l >> 4) * 4 + r;
        int col = bcol + wn * 64 + ni * 16 + (l & 15);
        C[(size_t)row * N + col] = acc[mi][ni][r] * gscale + bias_r[ni];
      }
    }
  }
}

// ---------------- launch ----------------

extern "C" void kernel_launch(void* const* d_in, const int* in_sizes, int n_in,
                              void* d_out, int out_size, void* d_ws, size_t ws_size,
                              hipStream_t stream) {
  const float* x    = (const float*)d_in[0];
  const float* wgt  = (const float*)d_in[1];
  const float* bias = (const float*)d_in[2];
  const float* isc  = (const float*)d_in[3];
  const float* wsc  = (const float*)d_in[4];
  float* out = (float*)d_out;

  const int N = in_sizes[2];            // 4096
  const int K = in_sizes[1] / N;        // 4096
  const int M = in_sizes[0] / K;        // 8192

  unsigned short* Aq = (unsigned short*)d_ws;
  unsigned short* Bq = Aq + (size_t)M * K;

  int nblkA = M * K / 16;
  quant_nvfp4<<<(nblkA + 255) / 256, 256, 0, stream>>>(x, Aq, isc, nblkA);
  int nblkB = N * K / 16;
  quant_nvfp4<<<(nblkB + 255) / 256, 256, 0, stream>>>(wgt, Bq, wsc, nblkB);

  dim3 grid((M / BM) * (N / BN));
  gemm_bt_bf16<<<grid, 512, 0, stream>>>(Aq, Bq, bias, isc, wsc, out, M, N, K);
}

// Round 4
// 275.079 us; speedup vs baseline: 1.5515x; 1.1120x over previous
//
#include <hip/hip_runtime.h>
#include <hip/hip_bf16.h>
#include <stdint.h>

typedef __attribute__((ext_vector_type(8))) __bf16 bf16x8;
typedef __attribute__((ext_vector_type(4))) float f32x4;
typedef __attribute__((ext_vector_type(4))) unsigned int u32x4;

#define BM 256
#define BN 256
#define BKT 32            // K per ring slot
#define RING 4            // prefetch depth 3
#define SLOT_BYTES 16384  // 256 rows x 32 cols x 2B

// ---------------- NVFP4 quantize-dequantize (factored: no global scale) ----------------

__device__ __forceinline__ float fp8_e4m3_rne(float x) {
  if (x < 0.015625f) {                       // below min normal 2^-6: subnormal grid 2^-9
    return rintf(x * 512.0f) * 0.001953125f;
  }
  uint32_t u = __float_as_uint(x);
  uint32_t keep = u & 0xFFF00000u;
  uint32_t rem  = u & 0x000FFFFFu;
  uint32_t lsb  = (u >> 20) & 1u;
  if (rem > 0x80000u || (rem == 0x80000u && lsb)) keep += 0x100000u;
  return __uint_as_float(keep);
}

__device__ __forceinline__ float snap_lvl(float a) {
  if (a > 5.0f)  return 6.0f;
  if (a > 3.5f)  return 4.0f;
  if (a > 2.5f)  return 3.0f;
  if (a > 1.75f) return 2.0f;
  if (a > 1.25f) return 1.5f;
  if (a > 0.75f) return 1.0f;
  if (a > 0.25f) return 0.5f;
  return 0.0f;
}

__global__ __launch_bounds__(256) void quant_nvfp4(
    const float* __restrict__ in, unsigned short* __restrict__ out,
    const float* __restrict__ gsp, int nblk) {
  int b = blockIdx.x * 256 + threadIdx.x;
  if (b >= nblk) return;
  float gs = gsp[0];
  const float4* p = reinterpret_cast<const float4*>(in) + (size_t)b * 4;
  float v[16];
#pragma unroll
  for (int i = 0; i < 4; ++i) {
    float4 t4 = p[i];
    v[i * 4 + 0] = t4.x; v[i * 4 + 1] = t4.y;
    v[i * 4 + 2] = t4.z; v[i * 4 + 3] = t4.w;
  }
  float amax = 0.0f;
#pragma unroll
  for (int i = 0; i < 16; ++i) amax = fmaxf(amax, fabsf(v[i]));
  float bs8 = fp8_e4m3_rne(amax / (6.0f * gs));
  float scale = fmaxf(bs8 * gs, 1e-12f);
  unsigned short o[16];
#pragma unroll
  for (int i = 0; i < 16; ++i) {
    float q = v[i] / scale;
    float a = fminf(fabsf(q), 6.0f);
    float val = copysignf(snap_lvl(a) * bs8, q);
    o[i] = (unsigned short)(__float_as_uint(val) >> 16);
  }
  uint4 w0 = make_uint4((uint32_t)o[0] | ((uint32_t)o[1] << 16),
                        (uint32_t)o[2] | ((uint32_t)o[3] << 16),
                        (uint32_t)o[4] | ((uint32_t)o[5] << 16),
                        (uint32_t)o[6] | ((uint32_t)o[7] << 16));
  uint4 w1 = make_uint4((uint32_t)o[8]  | ((uint32_t)o[9]  << 16),
                        (uint32_t)o[10] | ((uint32_t)o[11] << 16),
                        (uint32_t)o[12] | ((uint32_t)o[13] << 16),
                        (uint32_t)o[14] | ((uint32_t)o[15] << 16));
  uint4* op = reinterpret_cast<uint4*>(out + (size_t)b * 16);
  op[0] = w0;
  op[1] = w1;
}

// ---------------- bf16 GEMM, C = A * B^T ; 256x256 tile, ring-4 BK=32 ----------------

__device__ __forceinline__ void async_lds16(const void* g, void* l) {
  __builtin_amdgcn_global_load_lds((__attribute__((address_space(1))) void*)(g),
                                   (__attribute__((address_space(3))) void*)(l),
                                   16, 0, 0);
}

// ordered LDS vector read (volatile asm preserves mutual order -> lgkm counts exact)
#define DSR(dst, a) asm volatile("ds_read_b128 %0, %1" : "=v"(dst) : "v"(a))
#define LGKM(N) do { asm volatile("s_waitcnt lgkmcnt(" #N ")" ::: "memory"); \
                     __builtin_amdgcn_sched_barrier(0); } while (0)
#define BCB(x) __builtin_bit_cast(bf16x8, x)

#define MF4(mi, ar) do {                                                       \
    acc[mi][0] = __builtin_amdgcn_mfma_f32_16x16x32_bf16(BCB(ar), BCB(rb0), acc[mi][0], 0, 0, 0); \
    acc[mi][1] = __builtin_amdgcn_mfma_f32_16x16x32_bf16(BCB(ar), BCB(rb1), acc[mi][1], 0, 0, 0); \
    acc[mi][2] = __builtin_amdgcn_mfma_f32_16x16x32_bf16(BCB(ar), BCB(rb2), acc[mi][2], 0, 0, 0); \
    acc[mi][3] = __builtin_amdgcn_mfma_f32_16x16x32_bf16(BCB(ar), BCB(rb3), acc[mi][3], 0, 0, 0); \
  } while (0)

// one K32 tile: PH0 {8 reads, stage lo, barrier, 16 MFMA via counted lgkm}
//               PH1 {4 reads, stage hi, vmcnt, barrier, 16 MFMA via counted lgkm}
#define TILE(T, DO_STAGE, VMWAIT) do {                                         \
    const unsigned soff = (unsigned)(((T) & 3) * SLOT_BYTES);                  \
    u32x4 rb0, rb1, rb2, rb3, ra0, ra1, ra2, ra3;                              \
    DSR(rb0, adB[0] + soff); DSR(rb1, adB[1] + soff);                          \
    DSR(rb2, adB[2] + soff); DSR(rb3, adB[3] + soff);                          \
    DSR(ra0, adA[0] + soff); DSR(ra1, adA[1] + soff);                          \
    DSR(ra2, adA[2] + soff); DSR(ra3, adA[3] + soff);                          \
    if (DO_STAGE) {                                                            \
      char* _la = (char*)As + (((T) + 3) & 3) * SLOT_BYTES;                    \
      char* _lb = (char*)Bs + (((T) + 3) & 3) * SLOT_BYTES;                    \
      async_lds16(pA0 + (size_t)((T) + 3) * BKT, _la + lo0);                   \
      async_lds16(pB0 + (size_t)((T) + 3) * BKT, _lb + lo0);                   \
    }                                                                          \
    __builtin_amdgcn_sched_barrier(0);                                         \
    __builtin_amdgcn_s_barrier();                                              \
    LGKM(3); __builtin_amdgcn_s_setprio(1); MF4(0, ra0);                       \
    LGKM(2); MF4(1, ra1);                                                      \
    LGKM(1); MF4(2, ra2);                                                      \
    LGKM(0); MF4(3, ra3);                                                      \
    __builtin_amdgcn_s_setprio(0);                                             \
    __builtin_amdgcn_sched_barrier(0);                                         \
    DSR(ra0, adA[4] + soff); DSR(ra1, adA[5] + soff);                          \
    DSR(ra2, adA[6] + soff); DSR(ra3, adA[7] + soff);                          \
    if (DO_STAGE) {                                                            \
      char* _la = (char*)As + (((T) + 3) & 3) * SLOT_BYTES;                    \
      char* _lb = (char*)Bs + (((T) + 3) & 3) * SLOT_BYTES;                    \
      async_lds16(pA1 + (size_t)((T) + 3) * BKT, _la + lo1);                   \
      async_lds16(pB1 + (size_t)((T) + 3) * BKT, _lb + lo1);                   \
    }                                                                          \
    __builtin_amdgcn_sched_barrier(0);                                         \
    VMWAIT;                                                                    \
    __builtin_amdgcn_s_barrier();                                              \
    LGKM(3); __builtin_amdgcn_s_setprio(1); MF4(4, ra0);                       \
    LGKM(2); MF4(5, ra1);                                                      \
    LGKM(1); MF4(6, ra2);                                                      \
    LGKM(0); MF4(7, ra3);                                                      \
    __builtin_amdgcn_s_setprio(0);                                             \
    __builtin_amdgcn_sched_barrier(0);                                         \
  } while (0)

#define STAGE_TILE(s) {                                                        \
    char* _la = (char*)As + ((s) & 3) * SLOT_BYTES;                            \
    char* _lb = (char*)Bs + ((s) & 3) * SLOT_BYTES;                            \
    async_lds16(pA0 + (size_t)(s) * BKT, _la + lo0);                           \
    async_lds16(pB0 + (size_t)(s) * BKT, _lb + lo0);                           \
    async_lds16(pA1 + (size_t)(s) * BKT, _la + lo1);                           \
    async_lds16(pB1 + (size_t)(s) * BKT, _lb + lo1);                           \
  }

__global__ __launch_bounds__(512, 2) void gemm_bt_bf16(
    const unsigned short* __restrict__ A, const unsigned short* __restrict__ B,
    const float* __restrict__ bias, const float* __restrict__ gsx,
    const float* __restrict__ gsw, float* __restrict__ C,
    int M, int N, int K) {
  __shared__ __align__(16) unsigned short As[RING * 8192];
  __shared__ __align__(16) unsigned short Bs[RING * 8192];

  const int t = threadIdx.x;
  const int l = t & 63;
  const int w = t >> 6;
  const int wm = w >> 2, wn = w & 3;     // 2x4 waves; wave tile = 128(M) x 64(N)

  // bijective XCD swizzle (nwg = 512, divisible by 8)
  const int nbn = N / BN;
  const int nwg = (M / BM) * nbn;
  const int cpx = nwg >> 3;
  int bid = blockIdx.x;
  int logical = (bid & 7) * cpx + (bid >> 3);
  const int bm = logical / nbn, bn = logical % nbn;
  const int brow = bm * BM, bcol = bn * BN;

  // staging: linear LDS dest, inverse-swizzled global source (involution q^(((q>>7)&3)<<4))
  unsigned int b0 = (unsigned int)t * 16u;
  unsigned int b1 = b0 + 8192u;
  unsigned int bp0 = b0 ^ (((b0 >> 7) & 3u) << 4);
  unsigned int bp1 = b1 ^ (((b1 >> 7) & 3u) << 4);
  const unsigned int lo0 = b0, lo1 = b1;
  const unsigned short* pA0 = A + (size_t)(brow + (bp0 >> 6)) * K + ((bp0 & 63u) >> 1);
  const unsigned short* pA1 = A + (size_t)(brow + (bp1 >> 6)) * K + ((bp1 & 63u) >> 1);
  const unsigned short* pB0 = B + (size_t)(bcol + (bp0 >> 6)) * K + ((bp0 & 63u) >> 1);
  const unsigned short* pB1 = B + (size_t)(bcol + (bp1 >> 6)) * K + ((bp1 & 63u) >> 1);

  // swizzled fragment read addresses (32-bit LDS offsets; flat low-32 == LDS offset)
  const unsigned baseAu = (unsigned)(uintptr_t)(&As[0]);
  const unsigned baseBu = (unsigned)(uintptr_t)(&Bs[0]);
  unsigned int adA[8], adB[4];
#pragma unroll
  for (int mi = 0; mi < 8; ++mi) {
    unsigned int r = wm * 128 + mi * 16 + (l & 15);
    unsigned int q = r * 64 + ((l >> 4) << 4);
    adA[mi] = baseAu + (q ^ (((q >> 7) & 3u) << 4));
  }
#pragma unroll
  for (int ni = 0; ni < 4; ++ni) {
    unsigned int r = wn * 64 + ni * 16 + (l & 15);
    unsigned int q = r * 64 + ((l >> 4) << 4);
    adB[ni] = baseBu + (q ^ (((q >> 7) & 3u) << 4));
  }

  f32x4 acc[8][4] = {};

  const int nsub = K / BKT;   // 128

  // prologue: stage tiles 0..2, confirm tile 0 (tiles 1,2 = 8 loads stay in flight)
  STAGE_TILE(0);
  STAGE_TILE(1);
  STAGE_TILE(2);
  asm volatile("s_waitcnt vmcnt(8)" ::: "memory");
  __builtin_amdgcn_s_barrier();

#pragma unroll 1
  for (int T = 0; T < nsub - 3; ++T) {
    TILE(T, 1, asm volatile("s_waitcnt vmcnt(8)" ::: "memory"));
  }
  TILE(nsub - 3, 0, asm volatile("s_waitcnt vmcnt(4)" ::: "memory"));
  TILE(nsub - 2, 0, asm volatile("s_waitcnt vmcnt(0)" ::: "memory"));
  TILE(nsub - 1, 0, (void)0);

  // ---- epilogue ----
  const float gscale = gsx[0] * gsw[0];
  float bias_r[4];
#pragma unroll
  for (int ni = 0; ni < 4; ++ni)
    bias_r[ni] = bias[bcol + wn * 64 + ni * 16 + (l & 15)];
#pragma unroll
  for (int mi = 0; mi < 8; ++mi) {
#pragma unroll
    for (int ni = 0; ni < 4; ++ni) {
#pragma unroll
      for (int r = 0; r < 4; ++r) {
        int row = brow + wm * 128 + mi * 16 + (l >> 4) * 4 + r;
        int col = bcol + wn * 64 + ni * 16 + (l & 15);
        C[(size_t)row * N + col] = acc[mi][ni][r] * gscale + bias_r[ni];
      }
    }
  }
}

// ---------------- launch ----------------

extern "C" void kernel_launch(void* const* d_in, const int* in_sizes, int n_in,
                              void* d_out, int out_size, void* d_ws, size_t ws_size,
                              hipStream_t stream) {
  const float* x    = (const float*)d_in[0];
  const float* wgt  = (const float*)d_in[1];
  const float* bias = (const float*)d_in[2];
  const float* isc  = (const float*)d_in[3];
  const float* wsc  = (const float*)d_in[4];
  float* out = (float*)d_out;

  const int N = in_sizes[2];            // 4096
  const int K = in_sizes[1] / N;        // 4096
  const int M = in_sizes[0] / K;        // 8192

  unsigned short* Aq = (unsigned short*)d_ws;
  unsigned short* Bq = Aq + (size_t)M * K;

  int nblkA = M * K / 16;
  quant_nvfp4<<<(nblkA + 255) / 256, 256, 0, stream>>>(x, Aq, isc, nblkA);
  int nblkB = N * K / 16;
  quant_nvfp4<<<(nblkB + 255) / 256, 256, 0, stream>>>(wgt, Bq, wsc, nblkB);

  dim3 grid((M / BM) * (N / BN));
  gemm_bt_bf16<<<grid, 512, 0, stream>>>(Aq, Bq, bias, isc, wsc, out, M, N, K);
}